// Round 1
// baseline (3121.392 us; speedup 1.0000x reference)
//
#include <hip/hip_runtime.h>
#include <math.h>

#define NN 100000
#define EE 1600000
#define GG 1000

// ---- counts[g] += 1 per node ------------------------------------------------
__global__ void k_counts(const int* __restrict__ batch, float* __restrict__ counts, int n) {
    int i = blockIdx.x * blockDim.x + threadIdx.x;
    if (i < n) atomicAdd(&counts[batch[i]], 1.0f);
}

// ---- out[r][c] = sum_k in'[r][k] * W[k][c] ---------------------------------
// ACT: in'[r][k] = sigmoid(in[r][k]/cpn[r] + bPrev[k]); else in' = in.
// Block = 256 threads -> 4 rows/block, one output element per thread.
template<bool ACT>
__global__ void k_gemm64(const float* __restrict__ in, const float* __restrict__ W,
                         const float* __restrict__ bPrev, const float* __restrict__ counts,
                         const int* __restrict__ batch, float* __restrict__ out, int n) {
    __shared__ float Ws[64 * 64];
    __shared__ float Rs[4][64];
    int tid = threadIdx.x;

    // stage W (16 KB) via float4: 4096 floats / 256 threads = 4 float4 each
    const float4* W4 = (const float4*)W;
    float4* Ws4 = (float4*)Ws;
#pragma unroll
    for (int i = 0; i < 4; i++) Ws4[tid + 256 * i] = W4[tid + 256 * i];

    int r = tid >> 6;        // 0..3
    int c = tid & 63;        // 0..63
    int row = blockIdx.x * 4 + r;
    float v = 0.f;
    if (row < n) {
        v = in[(size_t)row * 64 + c];
        if (ACT) {
            float cp = counts[batch[row]];
            v = v / cp + bPrev[c];
            v = 1.f / (1.f + __expf(-v));
        }
    }
    Rs[r][c] = v;
    __syncthreads();

    float acc = 0.f;
#pragma unroll
    for (int k = 0; k < 64; k++)
        acc = fmaf(Rs[r][k], Ws[k * 64 + c], acc);   // Ws: 2-way bank alias (free); Rs: broadcast
    if (row < n) out[(size_t)row * 64 + c] = acc;
}

// ---- agg[dst] += ew * t[src]  (64 channels, 16 threads/edge, float4) -------
__global__ void k_scatter64(const float* __restrict__ t, const int* __restrict__ src,
                            const int* __restrict__ dst, const float* __restrict__ ew,
                            float* __restrict__ agg, int E) {
    int tid = blockIdx.x * blockDim.x + threadIdx.x;
    int e = tid >> 4;
    if (e >= E) return;
    int c4 = (tid & 15) * 4;
    int s = src[e], d = dst[e];
    float w = ew[e];
    float4 v = *(const float4*)(t + (size_t)s * 64 + c4);
    float* a = agg + (size_t)d * 64 + c4;
    atomicAdd(a + 0, v.x * w);
    atomicAdd(a + 1, v.y * w);
    atomicAdd(a + 2, v.z * w);
    atomicAdd(a + 3, v.w * w);
}

// ---- y[n] = dot(sigmoid(agg2[n]/cpn + b2), W3)  (wave-64 per node) ---------
__global__ void k_ydot(const float* __restrict__ agg2, const float* __restrict__ b2,
                       const float* __restrict__ W3, const float* __restrict__ counts,
                       const int* __restrict__ batch, float* __restrict__ y, int n) {
    int tid = blockIdx.x * blockDim.x + threadIdx.x;
    int node = tid >> 6;
    int lane = tid & 63;
    if (node >= n) return;
    float cp = counts[batch[node]];
    float v = agg2[(size_t)node * 64 + lane] / cp + b2[lane];
    v = 1.f / (1.f + __expf(-v));
    v *= W3[lane];
#pragma unroll
    for (int off = 32; off > 0; off >>= 1) v += __shfl_down(v, off, 64);
    if (lane == 0) y[node] = v;
}

// ---- agg3[dst] += ew * y[src]  (scalar) ------------------------------------
__global__ void k_scatter1(const float* __restrict__ y, const int* __restrict__ src,
                           const int* __restrict__ dst, const float* __restrict__ ew,
                           float* __restrict__ agg3, int E) {
    int e = blockIdx.x * blockDim.x + threadIdx.x;
    if (e >= E) return;
    atomicAdd(&agg3[dst[e]], ew[e] * y[src[e]]);
}

// ---- out[g] += (agg3[n]/cpn + b3)/cpn --------------------------------------
__global__ void k_pool(const float* __restrict__ agg3, const float* __restrict__ b3p,
                       const float* __restrict__ counts, const int* __restrict__ batch,
                       float* __restrict__ out, int n) {
    int i = blockIdx.x * blockDim.x + threadIdx.x;
    if (i >= n) return;
    int b = batch[i];
    float c = counts[b];
    float v = (agg3[i] / c + b3p[0]) / c;
    atomicAdd(&out[b], v);
}

extern "C" void kernel_launch(void* const* d_in, const int* in_sizes, int n_in,
                              void* d_out, int out_size, void* d_ws, size_t ws_size,
                              hipStream_t stream) {
    const float* x     = (const float*)d_in[0];
    const int*   ei    = (const int*)d_in[1];
    const int*   src   = ei;
    const int*   dst   = ei + EE;
    const float* ew    = (const float*)d_in[2];
    const int*   batch = (const int*)d_in[3];
    const float* W1    = (const float*)d_in[4];
    const float* b1    = (const float*)d_in[5];
    const float* W2    = (const float*)d_in[6];
    const float* b2    = (const float*)d_in[7];
    const float* W3    = (const float*)d_in[8];
    const float* b3    = (const float*)d_in[9];
    float* out = (float*)d_out;

    float* t      = (float*)d_ws;                  // N*64
    float* agg    = t + (size_t)NN * 64;           // N*64
    float* agg3   = agg + (size_t)NN * 64;         // N
    float* y      = agg3 + NN;                     // N
    float* counts = y + NN;                        // G

    // counts
    hipMemsetAsync(counts, 0, GG * sizeof(float), stream);
    k_counts<<<(NN + 255) / 256, 256, 0, stream>>>(batch, counts, NN);

    // layer 1: t = x @ W1 ; agg = scatter(t)
    k_gemm64<false><<<(NN + 3) / 4, 256, 0, stream>>>(x, W1, nullptr, nullptr, nullptr, t, NN);
    hipMemsetAsync(agg, 0, (size_t)NN * 64 * sizeof(float), stream);
    k_scatter64<<<((size_t)EE * 16 + 255) / 256, 256, 0, stream>>>(t, src, dst, ew, agg, EE);

    // layer 2: t = sigmoid(agg/cpn + b1) @ W2 ; agg = scatter(t)
    k_gemm64<true><<<(NN + 3) / 4, 256, 0, stream>>>(agg, W2, b1, counts, batch, t, NN);
    hipMemsetAsync(agg, 0, (size_t)NN * 64 * sizeof(float), stream);
    k_scatter64<<<((size_t)EE * 16 + 255) / 256, 256, 0, stream>>>(t, src, dst, ew, agg, EE);

    // layer 3 (W3 folded before the scatter -> scalar per edge)
    k_ydot<<<((size_t)NN * 64 + 255) / 256, 256, 0, stream>>>(agg, b2, W3, counts, batch, y, NN);
    hipMemsetAsync(agg3, 0, NN * sizeof(float), stream);
    k_scatter1<<<(EE + 255) / 256, 256, 0, stream>>>(y, src, dst, ew, agg3, EE);

    // pool
    hipMemsetAsync(out, 0, GG * sizeof(float), stream);
    k_pool<<<(NN + 255) / 256, 256, 0, stream>>>(agg3, b3, counts, batch, out, NN);
}

// Round 2
// 700.410 us; speedup vs baseline: 4.4565x; 4.4565x over previous
//
#include <hip/hip_runtime.h>
#include <math.h>

#define NN 100000
#define EE 1600000
#define GG 1000
#define SB 512                      // scan block (elements == threads)
#define NB1 ((NN + SB - 1) / SB)    // 196 scan blocks

// ---- counts[g] += 1 per node ------------------------------------------------
__global__ void k_counts(const int* __restrict__ batch, float* __restrict__ counts, int n) {
    int i = blockIdx.x * blockDim.x + threadIdx.x;
    if (i < n) atomicAdd(&counts[batch[i]], 1.0f);
}

// ---- hist[dst[e]]++ ---------------------------------------------------------
__global__ void k_hist(const int* __restrict__ dst, int* __restrict__ hist, int E) {
    int e = blockIdx.x * blockDim.x + threadIdx.x;
    if (e < E) atomicAdd(&hist[dst[e]], 1);
}

// ---- per-block inclusive scan of hist -> incl (stored in rowptr), partials --
__global__ void k_scan1(const int* __restrict__ hist, int* __restrict__ incl,
                        int* __restrict__ partials, int n) {
    __shared__ int s[SB];
    int i = blockIdx.x * SB + threadIdx.x;
    int v = (i < n) ? hist[i] : 0;
    s[threadIdx.x] = v;
    __syncthreads();
    for (int off = 1; off < SB; off <<= 1) {
        int t = (threadIdx.x >= off) ? s[threadIdx.x - off] : 0;
        __syncthreads();
        s[threadIdx.x] += t;
        __syncthreads();
    }
    if (i < n) incl[i] = s[threadIdx.x];
    if (threadIdx.x == SB - 1) partials[blockIdx.x] = s[SB - 1];
}

// ---- single-block exclusive scan of partials (NB1 <= 256) ------------------
__global__ void k_scan2(int* __restrict__ partials, int nb) {
    __shared__ int s[256];
    int v = (threadIdx.x < nb) ? partials[threadIdx.x] : 0;
    s[threadIdx.x] = v;
    __syncthreads();
    for (int off = 1; off < 256; off <<= 1) {
        int t = (threadIdx.x >= off) ? s[threadIdx.x - off] : 0;
        __syncthreads();
        s[threadIdx.x] += t;
        __syncthreads();
    }
    if (threadIdx.x < nb) partials[threadIdx.x] = s[threadIdx.x] - v; // exclusive
}

// ---- rowptr[i] = exclusive prefix; cursor[i] = same; rowptr[n] = E ----------
__global__ void k_scan3(const int* __restrict__ hist, int* __restrict__ rowptr,
                        const int* __restrict__ partials, int* __restrict__ cursor, int n, int E) {
    int i = blockIdx.x * SB + threadIdx.x;
    if (i < n) {
        int ex = rowptr[i] - hist[i] + partials[blockIdx.x];
        rowptr[i] = ex;
        cursor[i] = ex;
    }
    if (i == 0) rowptr[n] = E;
}

// ---- reorder edges into CSR: es[pos]=src, wf[pos]=w -------------------------
__global__ void k_reorder(const int* __restrict__ src, const int* __restrict__ dst,
                          const float* __restrict__ ew, int* __restrict__ cursor,
                          int* __restrict__ es, float* __restrict__ wf, int E) {
    int e = blockIdx.x * blockDim.x + threadIdx.x;
    if (e >= E) return;
    int d = dst[e];
    int pos = atomicAdd(&cursor[d], 1);
    es[pos] = src[e];
    wf[pos] = ew[e];
}

// ---- out[r][c] = sum_k in'[r][k] * W[k][c] ---------------------------------
// ACT: in'[r][k] = sigmoid(in[r][k]/cpn[r] + bPrev[k]); else in' = in.
template<bool ACT>
__global__ void k_gemm64(const float* __restrict__ in, const float* __restrict__ W,
                         const float* __restrict__ bPrev, const float* __restrict__ counts,
                         const int* __restrict__ batch, float* __restrict__ out, int n) {
    __shared__ float Ws[64 * 64];
    __shared__ float Rs[4][64];
    int tid = threadIdx.x;
    const float4* W4 = (const float4*)W;
    float4* Ws4 = (float4*)Ws;
#pragma unroll
    for (int i = 0; i < 4; i++) Ws4[tid + 256 * i] = W4[tid + 256 * i];

    int r = tid >> 6;
    int c = tid & 63;
    int row = blockIdx.x * 4 + r;
    float v = 0.f;
    if (row < n) {
        v = in[(size_t)row * 64 + c];
        if (ACT) {
            float cp = counts[batch[row]];
            v = v / cp + bPrev[c];
            v = 1.f / (1.f + __expf(-v));
        }
    }
    Rs[r][c] = v;
    __syncthreads();

    float acc = 0.f;
#pragma unroll
    for (int k = 0; k < 64; k++)
        acc = fmaf(Rs[r][k], Ws[k * 64 + c], acc);
    if (row < n) out[(size_t)row * 64 + c] = acc;
}

// ---- agg[node][lane] = sum_{e in CSR[node]} wf[e] * t[es[e]][lane] ---------
// one wave (64 lanes) per node, lane = channel; no atomics
__global__ void k_gather64(const float* __restrict__ t, const int* __restrict__ rowptr,
                           const int* __restrict__ es, const float* __restrict__ wf,
                           float* __restrict__ agg, int n) {
    int wid = (blockIdx.x * blockDim.x + threadIdx.x) >> 6;
    int lane = threadIdx.x & 63;
    wid = __builtin_amdgcn_readfirstlane(wid);   // wave-uniform -> scalar loads below
    if (wid >= n) return;
    int beg = rowptr[wid], end = rowptr[wid + 1];
    float acc = 0.f;
    for (int e = beg; e < end; e++) {
        int s = es[e];
        float w = wf[e];
        acc = fmaf(w, t[(size_t)s * 64 + lane], acc);
    }
    agg[(size_t)wid * 64 + lane] = acc;
}

// ---- y[n] = dot(sigmoid(agg2[n]/cpn + b2), W3)  (wave-64 per node) ---------
__global__ void k_ydot(const float* __restrict__ agg2, const float* __restrict__ b2,
                       const float* __restrict__ W3, const float* __restrict__ counts,
                       const int* __restrict__ batch, float* __restrict__ y, int n) {
    int tid = blockIdx.x * blockDim.x + threadIdx.x;
    int node = tid >> 6;
    int lane = tid & 63;
    if (node >= n) return;
    float cp = counts[batch[node]];
    float v = agg2[(size_t)node * 64 + lane] / cp + b2[lane];
    v = 1.f / (1.f + __expf(-v));
    v *= W3[lane];
#pragma unroll
    for (int off = 32; off > 0; off >>= 1) v += __shfl_down(v, off, 64);
    if (lane == 0) y[node] = v;
}

// ---- per-node layer-3 gather fused with graph-mean pool --------------------
__global__ void k_gather1_pool(const float* __restrict__ y, const int* __restrict__ rowptr,
                               const int* __restrict__ es, const float* __restrict__ wf,
                               const float* __restrict__ b3, const float* __restrict__ counts,
                               const int* __restrict__ batch, float* __restrict__ out, int n) {
    int i = blockIdx.x * blockDim.x + threadIdx.x;
    if (i >= n) return;
    int beg = rowptr[i], end = rowptr[i + 1];
    float acc = 0.f;
    for (int e = beg; e < end; e++) acc = fmaf(wf[e], y[es[e]], acc);
    int b = batch[i];
    float c = counts[b];
    atomicAdd(&out[b], (acc / c + b3[0]) / c);
}

extern "C" void kernel_launch(void* const* d_in, const int* in_sizes, int n_in,
                              void* d_out, int out_size, void* d_ws, size_t ws_size,
                              hipStream_t stream) {
    const float* x     = (const float*)d_in[0];
    const int*   ei    = (const int*)d_in[1];
    const int*   src   = ei;
    const int*   dst   = ei + EE;
    const float* ew    = (const float*)d_in[2];
    const int*   batch = (const int*)d_in[3];
    const float* W1    = (const float*)d_in[4];
    const float* b1    = (const float*)d_in[5];
    const float* W2    = (const float*)d_in[6];
    const float* b2    = (const float*)d_in[7];
    const float* W3    = (const float*)d_in[8];
    const float* b3    = (const float*)d_in[9];
    float* out = (float*)d_out;

    // workspace carve-up
    float* t      = (float*)d_ws;                      // N*64 floats
    float* agg    = t + (size_t)NN * 64;               // N*64 floats
    float* y      = agg + (size_t)NN * 64;             // N floats
    float* counts = y + NN;                            // G floats
    float* wf     = counts + GG;                       // E floats (CSR weights)
    int*   es     = (int*)(wf + EE);                   // E ints   (CSR srcs)
    int*   hist   = es + EE;                           // N ints
    int*   rowptr = hist + NN;                         // N+1 ints
    int*   cursor = rowptr + NN + 1;                   // N ints
    int*   partials = cursor + NN;                     // NB1 ints

    // counts + CSR build
    hipMemsetAsync(counts, 0, GG * sizeof(float), stream);
    hipMemsetAsync(hist, 0, NN * sizeof(int), stream);
    k_counts<<<(NN + 255) / 256, 256, 0, stream>>>(batch, counts, NN);
    k_hist<<<(EE + 255) / 256, 256, 0, stream>>>(dst, hist, EE);
    k_scan1<<<NB1, SB, 0, stream>>>(hist, rowptr, partials, NN);
    k_scan2<<<1, 256, 0, stream>>>(partials, NB1);
    k_scan3<<<NB1, SB, 0, stream>>>(hist, rowptr, partials, cursor, NN, EE);
    k_reorder<<<(EE + 255) / 256, 256, 0, stream>>>(src, dst, ew, cursor, es, wf, EE);

    // layer 1: t = x @ W1 ; agg = gather(t)
    k_gemm64<false><<<(NN + 3) / 4, 256, 0, stream>>>(x, W1, nullptr, nullptr, nullptr, t, NN);
    k_gather64<<<((size_t)NN * 64 + 255) / 256, 256, 0, stream>>>(t, rowptr, es, wf, agg, NN);

    // layer 2: t = sigmoid(agg/cpn + b1) @ W2 ; agg = gather(t)
    k_gemm64<true><<<(NN + 3) / 4, 256, 0, stream>>>(agg, W2, b1, counts, batch, t, NN);
    k_gather64<<<((size_t)NN * 64 + 255) / 256, 256, 0, stream>>>(t, rowptr, es, wf, agg, NN);

    // layer 3: y = sigmoid(agg/cpn+b2)·W3 ; pooled = gather1+pool
    k_ydot<<<((size_t)NN * 64 + 255) / 256, 256, 0, stream>>>(agg, b2, W3, counts, batch, y, NN);
    hipMemsetAsync(out, 0, GG * sizeof(float), stream);
    k_gather1_pool<<<(NN + 255) / 256, 256, 0, stream>>>(y, rowptr, es, wf, b3, counts, batch, out, NN);
}

// Round 3
// 693.291 us; speedup vs baseline: 4.5023x; 1.0103x over previous
//
#include <hip/hip_runtime.h>
#include <math.h>

#define NN 100000
#define EE 1600000
#define GG 1000
#define SB 512                      // scan block (elements == threads)
#define NB1 ((NN + SB - 1) / SB)    // 196 scan blocks

// ---- counts[g] += 1 per node ------------------------------------------------
__global__ void k_counts(const int* __restrict__ batch, float* __restrict__ counts, int n) {
    int i = blockIdx.x * blockDim.x + threadIdx.x;
    if (i < n) atomicAdd(&counts[batch[i]], 1.0f);
}

// ---- hist[dst[e]]++ ---------------------------------------------------------
__global__ void k_hist(const int* __restrict__ dst, int* __restrict__ hist, int E) {
    int e = blockIdx.x * blockDim.x + threadIdx.x;
    if (e < E) atomicAdd(&hist[dst[e]], 1);
}

// ---- per-block inclusive scan of hist -> incl (stored in rowptr), partials --
__global__ void k_scan1(const int* __restrict__ hist, int* __restrict__ incl,
                        int* __restrict__ partials, int n) {
    __shared__ int s[SB];
    int i = blockIdx.x * SB + threadIdx.x;
    int v = (i < n) ? hist[i] : 0;
    s[threadIdx.x] = v;
    __syncthreads();
    for (int off = 1; off < SB; off <<= 1) {
        int t = (threadIdx.x >= off) ? s[threadIdx.x - off] : 0;
        __syncthreads();
        s[threadIdx.x] += t;
        __syncthreads();
    }
    if (i < n) incl[i] = s[threadIdx.x];
    if (threadIdx.x == SB - 1) partials[blockIdx.x] = s[SB - 1];
}

// ---- single-block exclusive scan of partials (NB1 <= 256) ------------------
__global__ void k_scan2(int* __restrict__ partials, int nb) {
    __shared__ int s[256];
    int v = (threadIdx.x < nb) ? partials[threadIdx.x] : 0;
    s[threadIdx.x] = v;
    __syncthreads();
    for (int off = 1; off < 256; off <<= 1) {
        int t = (threadIdx.x >= off) ? s[threadIdx.x - off] : 0;
        __syncthreads();
        s[threadIdx.x] += t;
        __syncthreads();
    }
    if (threadIdx.x < nb) partials[threadIdx.x] = s[threadIdx.x] - v; // exclusive
}

// ---- rowptr[i] = exclusive prefix; cursor[i] = same; rowptr[n] = E ----------
__global__ void k_scan3(const int* __restrict__ hist, int* __restrict__ rowptr,
                        const int* __restrict__ partials, int* __restrict__ cursor, int n, int E) {
    int i = blockIdx.x * SB + threadIdx.x;
    if (i < n) {
        int ex = rowptr[i] - hist[i] + partials[blockIdx.x];
        rowptr[i] = ex;
        cursor[i] = ex;
    }
    if (i == 0) rowptr[n] = E;
}

// ---- reorder edges into CSR, packed (src, weight) in one 8B record ----------
__global__ void k_reorder(const int* __restrict__ src, const int* __restrict__ dst,
                          const float* __restrict__ ew, int* __restrict__ cursor,
                          uint2* __restrict__ ep, int E) {
    int e = blockIdx.x * blockDim.x + threadIdx.x;
    if (e >= E) return;
    int d = dst[e];
    unsigned s = (unsigned)src[e];
    unsigned w = __float_as_uint(ew[e]);
    int pos = atomicAdd(&cursor[d], 1);
    ep[pos] = make_uint2(s, w);
}

// ---- out[r][c] = sum_k in'[r][k] * W[k][c] ---------------------------------
// ACT: in'[r][k] = sigmoid(in[r][k]/cpn[r] + bPrev[k]); else in' = in.
template<bool ACT>
__global__ void k_gemm64(const float* __restrict__ in, const float* __restrict__ W,
                         const float* __restrict__ bPrev, const float* __restrict__ counts,
                         const int* __restrict__ batch, float* __restrict__ out, int n) {
    __shared__ float Ws[64 * 64];
    __shared__ float Rs[4][64];
    int tid = threadIdx.x;
    const float4* W4 = (const float4*)W;
    float4* Ws4 = (float4*)Ws;
#pragma unroll
    for (int i = 0; i < 4; i++) Ws4[tid + 256 * i] = W4[tid + 256 * i];

    int r = tid >> 6;
    int c = tid & 63;
    int row = blockIdx.x * 4 + r;
    float v = 0.f;
    if (row < n) {
        v = in[(size_t)row * 64 + c];
        if (ACT) {
            float cp = counts[batch[row]];
            v = v / cp + bPrev[c];
            v = 1.f / (1.f + __expf(-v));
        }
    }
    Rs[r][c] = v;
    __syncthreads();

    float acc = 0.f;
#pragma unroll
    for (int k = 0; k < 64; k++)
        acc = fmaf(Rs[r][k], Ws[k * 64 + c], acc);
    if (row < n) out[(size_t)row * 64 + c] = acc;
}

// ---- wave-per-node CSR gather; optionally fused sigmoid+dot(W3) epilogue ----
// FUSE_Y=false: agg[node][lane] = sum_e w_e * t[src_e][lane]
// FUSE_Y=true:  y[node] = sum_lane sigmoid(acc/cpn + b2[lane]) * W3[lane]
template<bool FUSE_Y>
__global__ void k_gather64(const float* __restrict__ t, const int* __restrict__ rowptr,
                           const uint2* __restrict__ ep, float* __restrict__ outp,
                           const float* __restrict__ b2, const float* __restrict__ W3,
                           const float* __restrict__ counts, const int* __restrict__ batch,
                           int n) {
    int wid = (blockIdx.x * blockDim.x + threadIdx.x) >> 6;
    int lane = threadIdx.x & 63;
    wid = __builtin_amdgcn_readfirstlane(wid);   // wave-uniform -> scalar edge loads
    if (wid >= n) return;
    int beg = rowptr[wid], end = rowptr[wid + 1];
    float acc = 0.f;
    for (int e = beg; e < end; e++) {
        uint2 r = ep[e];
        int s = (int)r.x;
        float w = __uint_as_float(r.y);
        acc = fmaf(w, t[(size_t)s * 64 + lane], acc);
    }
    if (!FUSE_Y) {
        outp[(size_t)wid * 64 + lane] = acc;
    } else {
        float cp = counts[batch[wid]];
        float v = acc / cp + b2[lane];
        v = 1.f / (1.f + __expf(-v));
        v *= W3[lane];
#pragma unroll
        for (int off = 32; off > 0; off >>= 1) v += __shfl_down(v, off, 64);
        if (lane == 0) outp[wid] = v;
    }
}

// ---- per-node layer-3 gather fused with graph-mean pool --------------------
__global__ void k_gather1_pool(const float* __restrict__ y, const int* __restrict__ rowptr,
                               const uint2* __restrict__ ep,
                               const float* __restrict__ b3, const float* __restrict__ counts,
                               const int* __restrict__ batch, float* __restrict__ out, int n) {
    int i = blockIdx.x * blockDim.x + threadIdx.x;
    if (i >= n) return;
    int beg = rowptr[i], end = rowptr[i + 1];
    float acc = 0.f;
    for (int e = beg; e < end; e++) {
        uint2 r = ep[e];
        acc = fmaf(__uint_as_float(r.y), y[(int)r.x], acc);
    }
    int b = batch[i];
    float c = counts[b];
    atomicAdd(&out[b], (acc / c + b3[0]) / c);
}

extern "C" void kernel_launch(void* const* d_in, const int* in_sizes, int n_in,
                              void* d_out, int out_size, void* d_ws, size_t ws_size,
                              hipStream_t stream) {
    const float* x     = (const float*)d_in[0];
    const int*   ei    = (const int*)d_in[1];
    const int*   src   = ei;
    const int*   dst   = ei + EE;
    const float* ew    = (const float*)d_in[2];
    const int*   batch = (const int*)d_in[3];
    const float* W1    = (const float*)d_in[4];
    const float* b1    = (const float*)d_in[5];
    const float* W2    = (const float*)d_in[6];
    const float* b2    = (const float*)d_in[7];
    const float* W3    = (const float*)d_in[8];
    const float* b3    = (const float*)d_in[9];
    float* out = (float*)d_out;

    // workspace carve-up
    float* t      = (float*)d_ws;                      // N*64 floats
    float* agg    = t + (size_t)NN * 64;               // N*64 floats
    float* y      = agg + (size_t)NN * 64;             // N floats
    float* counts = y + NN;                            // G floats
    uint2* ep     = (uint2*)(counts + GG);             // E uint2 (packed CSR records)
    int*   hist   = (int*)(ep + EE);                   // N ints
    int*   rowptr = hist + NN;                         // N+1 ints
    int*   cursor = rowptr + NN + 1;                   // N ints
    int*   partials = cursor + NN;                     // NB1 ints

    // counts + CSR build
    hipMemsetAsync(counts, 0, GG * sizeof(float), stream);
    hipMemsetAsync(hist, 0, NN * sizeof(int), stream);
    k_counts<<<(NN + 255) / 256, 256, 0, stream>>>(batch, counts, NN);
    k_hist<<<(EE + 255) / 256, 256, 0, stream>>>(dst, hist, EE);
    k_scan1<<<NB1, SB, 0, stream>>>(hist, rowptr, partials, NN);
    k_scan2<<<1, 256, 0, stream>>>(partials, NB1);
    k_scan3<<<NB1, SB, 0, stream>>>(hist, rowptr, partials, cursor, NN, EE);
    k_reorder<<<(EE + 255) / 256, 256, 0, stream>>>(src, dst, ew, cursor, ep, EE);

    // layer 1: t = x @ W1 ; agg = gather(t)
    k_gemm64<false><<<(NN + 3) / 4, 256, 0, stream>>>(x, W1, nullptr, nullptr, nullptr, t, NN);
    k_gather64<false><<<((size_t)NN * 64 + 255) / 256, 256, 0, stream>>>(
        t, rowptr, ep, agg, nullptr, nullptr, nullptr, nullptr, NN);

    // layer 2: t = sigmoid(agg/cpn + b1) @ W2 ; y = fused gather+sigmoid+dot(W3)
    k_gemm64<true><<<(NN + 3) / 4, 256, 0, stream>>>(agg, W2, b1, counts, batch, t, NN);
    k_gather64<true><<<((size_t)NN * 64 + 255) / 256, 256, 0, stream>>>(
        t, rowptr, ep, y, b2, W3, counts, batch, NN);

    // layer 3: pooled = gather1+pool
    hipMemsetAsync(out, 0, GG * sizeof(float), stream);
    k_gather1_pool<<<(NN + 255) / 256, 256, 0, stream>>>(y, rowptr, ep, b3, counts, batch, out, NN);
}